// Round 6
// baseline (186.370 us; speedup 1.0000x reference)
//
#include <hip/hip_runtime.h>

// Cost-volume / correlation layer, fp32.
// out[b, dy*9+dx, h, w] = (1/C) * sum_c first[b,c,h,w] * second[b,c,h+dy-4,w+dx-4]
// (zero outside bounds).  B=8, C=128, H=W=128, search_range=4 -> 81 offsets.
//
// Round-9: back to the R7 skeleton (83us, CORRECT).  R8's lesson: never mix
// compiler-invisible asm loads into a hand-counted vmcnt FIFO -> race, failed.
// R7 model (validated by VALUBusy 50%): per channel per CU, LDS pipe 864cy
// vs VALU 324cy vs measured 1556cy => ~700cy/channel is barrier/wait lockstep
// bubble, paid 128 times.  This round amortizes it: FOUR channels per barrier
// phase (32 phases), triple-buffered phase slabs (3 x 4 x 6KiB = 72KiB, still
// 2 blocks/CU).  All VMEM stays compiler-visible global_load_lds; per-wave
// FIFO is exactly [stage(p)x4, stage(p+1)x4] at each phase top -> vmcnt(4).
// stage(p+2) is issued AFTER the barrier, so buf (p-1)%3's readers (compute
// p-1, which drained lgkmcnt(0) before this barrier) are provably done.
// Predicted: ~4x fewer bubbles -> 1040cy/channel -> ~55-63us.

constexpr int B = 8, C = 128, H = 128, W = 128;
constexpr int RNG = 4, MO = 9;        // search range, max_offset
constexpr int RW  = 4;                // pixels per thread along w
constexpr int TH  = 2;                // h rows per block
constexpr int HWc = H * W;            // 16384
constexpr int CPP = 4;                // channels per phase
constexpr int NP  = C / CPP;          // 32 phases
constexpr int PBUF = 3;               // phase buffers
constexpr int SLABR = TH + TH + 2 * RNG;   // 12 rows: 2 first + 10 second
constexpr int SLAB  = SLABR * W;      // 1536 floats = 6 KiB per channel

typedef float f32x4 __attribute__((ext_vector_type(4)));

__global__ __launch_bounds__(576)
__attribute__((amdgpu_waves_per_eu(2, 5)))
void corr_kernel(const float* __restrict__ first,
                 const float* __restrict__ second,
                 float* __restrict__ out)
{
    const int tx = threadIdx.x;           // 0..31
    const int hy = threadIdx.y;           // 0..1
    const int dz = threadIdx.z;           // 0..8  (wave id == dz)
    const int h0 = blockIdx.x * TH;       // 0..126 (even)
    const int b  = blockIdx.y;
    const int w0 = tx * RW;               // 0..124
    const int lane = tx + 32 * hy;        // 0..63

    __shared__ __align__(16) float slab[PBUF][CPP][SLAB];   // 72 KiB

    // ---- staging roles (one 1KiB DMA per wave per channel), as R7: ----
    // wave 0: first rows (h0, h0+1) -> slab rows 0..1
    // waves 1..5: second row-pair q = dz-1: global rows (h0-4+2q, h0-4+2q+1)
    //   -> slab rows 2+2q..3+2q.  Pairs are even-aligned => fully-valid or
    //   fully-invalid; invalid pairs clamp-staged (finite, never read).
    const float* gsrc = nullptr;
    int ldsoff = 0;
    if (dz == 0) {
        gsrc  = first + (size_t)b * C * HWc + h0 * W + lane * 4;
        ldsoff = 0;
    } else if (dz <= 5) {
        const int q  = dz - 1;
        const int r0 = h0 - RNG + 2 * q;                  // even, [-4,130]
        const int cs = r0 < 0 ? 0 : (r0 > H - 2 ? H - 2 : r0);
        gsrc  = second + (size_t)b * C * HWc + cs * W + lane * 4;
        ldsoff = (TH + 2 * q) * W;
    }
    const bool do_stage = (dz <= 5);

    // ---- compute-side constants ----
    const int  srow   = h0 + hy + dz - RNG;
    const bool rvalid = (srow >= 0) && (srow < H);
    const bool ledge  = (tx == 0);
    const bool redge  = (tx == 31);
    const int off0  = ledge ? 0       : (w0 - 4);   // 16B-aligned in-row
    const int off2  = redge ? (W - 8) : (w0 + 4);
    const int fbase = hy * W + w0;                  // slab rows 0..1
    const int sbase = (TH + hy + dz) * W;           // slab row 2+hy+dz

    float acc[MO][RW];
#pragma unroll
    for (int i = 0; i < MO; ++i)
#pragma unroll
        for (int p = 0; p < RW; ++p) acc[i][p] = 0.0f;

#define FENCE asm volatile("" ::: "memory");

#define STAGE1(c, buf)                                                      \
    if (do_stage) {                                                         \
        __builtin_amdgcn_global_load_lds(                                   \
            (const __attribute__((address_space(1))) void*)                 \
                (gsrc + (size_t)(c) * HWc),                                 \
            (__attribute__((address_space(3))) void*)                       \
                (&slab[buf][(c) & (CPP - 1)][ldsoff]),                      \
            16, 0, 0);                                                      \
    }

#define STAGEP(p)                                                           \
    {                                                                       \
        const int _bp = (p) % PBUF;                                         \
        STAGE1((p) * CPP + 0, _bp)                                          \
        STAGE1((p) * CPP + 1, _bp)                                          \
        STAGE1((p) * CPP + 2, _bp)                                          \
        STAGE1((p) * CPP + 3, _bp)                                          \
    }

#define COMPUTE_PHASE(p)                                                    \
    {                                                                       \
        const float* pb = &slab[(p) % PBUF][0][0];                          \
        _Pragma("unroll")                                                   \
        for (int kc = 0; kc < CPP; ++kc) {                                  \
            const float* sc = pb + kc * SLAB;                               \
            f32x4 fv = *(const f32x4*)(sc + fbase);                         \
            f32x4 a0 = *(const f32x4*)(sc + sbase + off0);                  \
            f32x4 a1 = *(const f32x4*)(sc + sbase + w0);                    \
            f32x4 a2 = *(const f32x4*)(sc + sbase + off2);                  \
            if (ledge) a0 = (f32x4){0.f, 0.f, 0.f, 0.f};                    \
            if (redge) a2 = (f32x4){0.f, 0.f, 0.f, 0.f};                    \
            const float s[12] = {a0.x, a0.y, a0.z, a0.w,                    \
                                 a1.x, a1.y, a1.z, a1.w,                    \
                                 a2.x, a2.y, a2.z, a2.w};                   \
            const float fvv[RW] = {fv.x, fv.y, fv.z, fv.w};                 \
            _Pragma("unroll")                                               \
            for (int dx = 0; dx < MO; ++dx)                                 \
                _Pragma("unroll")                                           \
                for (int pp = 0; pp < RW; ++pp)                             \
                    acc[dx][pp] += fvv[pp] * s[pp + dx];                    \
        }                                                                   \
        asm volatile("s_waitcnt lgkmcnt(0)" ::: "memory");                  \
        __builtin_amdgcn_sched_barrier(0);                                  \
    }

    // prologue: fill phase buffers 0 and 1 (FIFO: [s0 x4, s1 x4])
    STAGEP(0)
    FENCE
    STAGEP(1)

    for (int p = 0; p < NP; ++p) {
        // entering FIFO (staging waves): [stage(p) x4, stage(p+1) x4]
        if (p < NP - 1) { asm volatile("s_waitcnt vmcnt(4)" ::: "memory"); }
        else            { asm volatile("s_waitcnt vmcnt(0)" ::: "memory"); }
        __builtin_amdgcn_sched_barrier(0);
        __builtin_amdgcn_s_barrier();        // buf p%3 published to all waves
        // stage(p+2) overwrites buf (p-1)%3: its readers (compute p-1)
        // drained lgkmcnt(0) before the barrier we just passed -> safe.
        if (p < NP - 2) STAGEP(p + 2)
        COMPUTE_PHASE(p)
    }

#undef COMPUTE_PHASE
#undef STAGEP
#undef STAGE1
#undef FENCE

    // invalid srow => result must be 0 (acc holds finite garbage; *0 is safe)
    const float inv = rvalid ? (1.0f / (float)C) : 0.0f;
    float* obase = out + ((size_t)b * (MO * MO) + (size_t)dz * MO) * HWc
                       + (size_t)(h0 + hy) * W + w0;
#pragma unroll
    for (int dx = 0; dx < MO; ++dx) {
        f32x4 v = {acc[dx][0] * inv, acc[dx][1] * inv,
                   acc[dx][2] * inv, acc[dx][3] * inv};
        *(f32x4*)(obase + (size_t)dx * HWc) = v;
    }
}

extern "C" void kernel_launch(void* const* d_in, const int* in_sizes, int n_in,
                              void* d_out, int out_size, void* d_ws, size_t ws_size,
                              hipStream_t stream) {
    const float* first  = (const float*)d_in[0];
    const float* second = (const float*)d_in[1];
    float* out = (float*)d_out;

    dim3 grid(H / TH, B);       // (64, 8) = 512 blocks = 2 per CU
    dim3 block(32, TH, MO);     // 576 threads = 9 waves, wave id == dy
    corr_kernel<<<grid, block, 0, stream>>>(first, second, out);
}